// Round 2
// baseline (1009.187 us; speedup 1.0000x reference)
//
#include <hip/hip_runtime.h>
#include <math.h>

// Problem constants (from reference)
#define N_NODES   100000
#define N_EDGES   1600000
#define NUM_RBF   128
#define NUM_GAUSS 32
#define NFEAT     160      // 128 + 32 -> 40 float4 columns per edge
#define CUTOFF    6.0f

#define EPB    64           // edges per chunk
#define BLOCK  320          // 5 waves; 320/40 = 8 edges per store iteration
#define COLS   40           // float4 columns per edge
#define EPI    (BLOCK/COLS) // 8 edges per iteration
#define NITER  (EPB/EPI)    // 8 iterations per chunk
#define NCHUNK (N_EDGES/EPB)// 25000 chunks
#define GRID   2500         // persistent-ish: exactly 10 chunks per block

static __device__ __forceinline__ float fast_exp2(float x) {
#if __has_builtin(__builtin_amdgcn_exp2f)
    return __builtin_amdgcn_exp2f(x);   // raw v_exp_f32 (D = 2^S0)
#else
    return __expf(0.6931471805599453f * x);
#endif
}

__global__ __launch_bounds__(BLOCK) void edge_feat_kernel(
    const float* __restrict__ pos,     // [N_NODES, 3]
    const int*   __restrict__ eidx,    // [2, N_EDGES]
    float*       __restrict__ out)     // [N_EDGES, 160]
{
    // Double-buffered per-edge scalars: (dist, cutoff, exp(-alpha*d), 0)
    __shared__ float4 s_edge[2][EPB];

    const int tid = threadIdx.x;
    const bool writer = (tid < EPB);   // wave 0 exactly

    // ---- Per-thread loop-invariant constants (fixed feature column) ----
    const int col   = tid % COLS;       // float4 column 0..39
    const int eiter = tid / COLS;       // edge slot within an iteration 0..7
    const bool isRBF = (col < NUM_RBF / 4);

    const float start = (float)0.0024787521766663585;            // exp(-6)
    const float mstep = (float)((1.0 - 0.0024787521766663585) / (NUM_RBF - 1));
    const float beta  = (float)(1.0 /
        ((2.0 / NUM_RBF * (1.0 - 0.0024787521766663585)) *
         (2.0 / NUM_RBF * (1.0 - 0.0024787521766663585))));      // ~4116.4
    const float gstep = (float)(10.0 / (NUM_GAUSS - 1));
    const float ginv  = 20.48f;                                   // 1/(2*w^2)
    const float LOG2E = 1.4426950408889634f;

    const int f0 = col * 4;
    float4 C;
    float SB;
    if (isRBF) {
        C.x = start + (float)(f0 + 0) * mstep;
        C.y = start + (float)(f0 + 1) * mstep;
        C.z = start + (float)(f0 + 2) * mstep;
        C.w = start + (float)(f0 + 3) * mstep;
        SB  = sqrtf(beta * LOG2E);
    } else {
        const int g0 = f0 - NUM_RBF;
        C.x = (float)(g0 + 0) * gstep;
        C.y = (float)(g0 + 1) * gstep;
        C.z = (float)(g0 + 2) * gstep;
        C.w = (float)(g0 + 3) * gstep;
        SB  = sqrtf(ginv * LOG2E);
    }

    // ---- Prologue: fill buffer 0 for this block's first chunk ----
    int c = blockIdx.x;                 // < NCHUNK always (GRID <= NCHUNK)
    if (writer) {
        const int e = c * EPB + tid;
        const int s = eidx[e];
        const int t = eidx[N_EDGES + e];
        const float dx = pos[3*s + 0] - pos[3*t + 0];
        const float dy = pos[3*s + 1] - pos[3*t + 1];
        const float dz = pos[3*s + 2] - pos[3*t + 2];
        const float dist = sqrtf(dx*dx + dy*dy + dz*dz + 1e-12f);
        const float cth = 0.5f * (__cosf(dist * (float)(M_PI / 6.0)) + 1.0f);
        const float cc = (dist < CUTOFF) ? cth : 0.0f;
        const float te = __expf(-(5.0f / 6.0f) * dist);
        s_edge[0][tid] = make_float4(dist, cc, te, 0.0f);
    }
    __syncthreads();

    // ---- Main loop: store chunk c while prefetching chunk c+GRID ----
    int buf = 0;
    for (; c < NCHUNK; c += GRID) {
        const int  cn  = c + GRID;
        const bool pre = writer && (cn < NCHUNK);

        // Stage A: issue the next chunk's gather loads (latency hides
        // under the store phase below)
        int   sA = 0, tA = 0;
        float ax = 0.f, ay = 0.f, az = 0.f, bx = 0.f, by = 0.f, bz = 0.f;
        if (pre) {
            const int e = cn * EPB + tid;
            sA = eidx[e];
            tA = eidx[N_EDGES + e];
            ax = pos[3*sA + 0]; ay = pos[3*sA + 1]; az = pos[3*sA + 2];
            bx = pos[3*tA + 0]; by = pos[3*tA + 1]; bz = pos[3*tA + 2];
        }

        // Store phase: 8 iterations, fully coalesced 1 KiB/wave stores
        float4* out4 = (float4*)(out + (size_t)c * EPB * NFEAT);
        #pragma unroll
        for (int k = 0; k < NITER; ++k) {
            const float4 es = s_edge[buf][k * EPI + eiter];  // LDS broadcast
            const float X = isRBF ? es.z : es.x;    // exp(-alpha*d) or d
            const float A = isRBF ? es.y : 1.0f;    // cutoff or 1
            float4 r;
            {
                const float vx = (X - C.x) * SB;
                const float vy = (X - C.y) * SB;
                const float vz = (X - C.z) * SB;
                const float vw = (X - C.w) * SB;
                r.x = A * fast_exp2(-vx * vx);
                r.y = A * fast_exp2(-vy * vy);
                r.z = A * fast_exp2(-vz * vz);
                r.w = A * fast_exp2(-vw * vw);
            }
            out4[k * BLOCK + tid] = r;
        }

        // Stage B: finish the prefetch (math + LDS write into other buffer)
        if (pre) {
            const float dx = ax - bx;
            const float dy = ay - by;
            const float dz = az - bz;
            const float dist = sqrtf(dx*dx + dy*dy + dz*dz + 1e-12f);
            const float cth = 0.5f * (__cosf(dist * (float)(M_PI / 6.0)) + 1.0f);
            const float cc = (dist < CUTOFF) ? cth : 0.0f;
            const float te = __expf(-(5.0f / 6.0f) * dist);
            s_edge[buf ^ 1][tid] = make_float4(dist, cc, te, 0.0f);
        }

        __syncthreads();   // one barrier per chunk separates the two buffers
        buf ^= 1;
    }
}

extern "C" void kernel_launch(void* const* d_in, const int* in_sizes, int n_in,
                              void* d_out, int out_size, void* d_ws, size_t ws_size,
                              hipStream_t stream) {
    const float* pos  = (const float*)d_in[0];
    const int*   eidx = (const int*)d_in[1];
    float*       out  = (float*)d_out;

    edge_feat_kernel<<<GRID, BLOCK, 0, stream>>>(pos, eidx, out);
}